// Round 9
// baseline (362.104 us; speedup 1.0000x reference)
//
#include <hip/hip_runtime.h>
#include <stdint.h>

typedef unsigned short u16;
typedef __attribute__((ext_vector_type(8))) short short8;
typedef __attribute__((ext_vector_type(4))) float f32x4;
typedef __attribute__((ext_vector_type(4))) float float4v;
typedef __attribute__((ext_vector_type(4))) unsigned short us4;
typedef __attribute__((ext_vector_type(8))) unsigned short us8;

#define TOK   8192      // B*S
#define DIN   1280
#define DHID  2048
#define NEXP  8
#define RCAP  17408     // 16384 pairs + 8*128 worst-case alignment pad
#define MT128 136       // RCAP/128

#define TRBLK1 5120     // 8 experts * (1280/64) * (2048/64)
#define TRBLK2 5120     // 8 experts * (2048/64) * (1280/64)
#define RTRBLKS 1024    // TOK/8

__device__ __forceinline__ float bf2f(u16 u) {
  union { unsigned int i; float f; } v; v.i = ((unsigned int)u) << 16; return v.f;
}
__device__ __forceinline__ u16 f2bf(float f) {
  union { float f; unsigned int i; } v; v.f = f;
  unsigned int x = v.i;
  return (u16)((x + 0x7fffu + ((x >> 16) & 1u)) >> 16);
}

__device__ __forceinline__ void gload16(const u16* g, void* lds) {
  __builtin_amdgcn_global_load_lds(
      (const __attribute__((address_space(1))) unsigned int*)g,
      (__attribute__((address_space(3))) unsigned int*)lds, 16, 0, 0);
}

// ---------------- fused pre-pass: wide-IO transpose(w1,w2) + router ----------------
// Transpose v2: 64x64 tile, float4 loads (16B/lane), ds_write_b16 into column-major
// [64][72] u16 LDS (conflict-free: whole wave writes one column), ds_read_b128 +
// 16B stores out. ~5x fewer global instructions than the 32x32 scalar version.
__global__ __launch_bounds__(256) void pre_k(
    const float* __restrict__ w1, u16* __restrict__ W1t,
    const float* __restrict__ w2, u16* __restrict__ W2t,
    const float* __restrict__ x, const float* __restrict__ noise,
    const float* __restrict__ wr, const float* __restrict__ br,
    const float* __restrict__ wn, const float* __restrict__ bn,
    int* __restrict__ topk_e, float* __restrict__ topk_g)
{
  __shared__ u16 ldsT[64 * 72];   // 9216 B; [col c][row r] with pad 72
  int id = blockIdx.x;
  int tid = threadIdx.x;
  int w = tid >> 6, lane = tid & 63;

  if (id < TRBLK1 + TRBLK2) {
    const float* in; u16* outp; int RK, CN, rb, cb;
    if (id < TRBLK1) {
      int e = id / 640, r = id % 640;
      RK = DIN; CN = DHID;                 // w1: [1280, 2048]
      rb = (r >> 5) * 64; cb = (r & 31) * 64;
      in = w1 + (size_t)e * RK * CN; outp = W1t + (size_t)e * RK * CN;
    } else {
      int id2 = id - TRBLK1;
      int e = id2 / 640, r = id2 % 640;
      RK = DHID; CN = DIN;                 // w2: [2048, 1280]
      rb = (r / 20) * 64; cb = (r % 20) * 64;
      in = w2 + (size_t)e * RK * CN; outp = W2t + (size_t)e * RK * CN;
    }
    {
      // wave w handles cols cb + w*16 .. +16; lane = row
      const float* src = in + (size_t)(rb + lane) * CN + cb + w * 16;
      u16 val[16];
      #pragma unroll
      for (int k = 0; k < 4; k++) {
        float4v v = *(const float4v*)(src + k * 4);
        #pragma unroll
        for (int j = 0; j < 4; j++) val[k * 4 + j] = f2bf(v[j]);
      }
      #pragma unroll
      for (int j = 0; j < 16; j++)
        ldsT[(w * 16 + j) * 72 + lane] = val[j];   // whole wave -> one column: 2 lanes/bank
    }
    __syncthreads();
    {
      int oc = tid >> 2, rch = (tid & 3) * 16;
      const u16* s = &ldsT[oc * 72 + rch];
      u16* d = outp + (size_t)(cb + oc) * RK + rb + rch;
      *(us8*)(d)     = *(const us8*)(s);
      *(us8*)(d + 8) = *(const us8*)(s + 8);
    }
    return;
  }

  // ---- router: 2 tokens/wave, float4 loads, no atomics ----
  int rid = id - (TRBLK1 + TRBLK2);
  int t0 = rid * 8 + w * 2;
  const float4v* xA = (const float4v*)(x + (size_t)t0 * DIN);
  const float4v* xB = (const float4v*)(x + (size_t)(t0 + 1) * DIN);
  float accA[16], accB[16];
  #pragma unroll
  for (int k = 0; k < 16; k++) { accA[k] = 0.f; accB[k] = 0.f; }

  #pragma unroll
  for (int i = 0; i < 5; i++) {
    int d4 = i * 64 + lane;
    float4v va = xA[d4];
    float4v vb = xB[d4];
    #pragma unroll
    for (int j = 0; j < 4; j++) {
      int d = d4 * 4 + j;
      const float4v* wrp = (const float4v*)(wr + (size_t)d * 8);
      const float4v* wnp = (const float4v*)(wn + (size_t)d * 8);
      float4v r0 = wrp[0], r1 = wrp[1], n0 = wnp[0], n1 = wnp[1];
      float a = va[j], b = vb[j];
      #pragma unroll
      for (int e = 0; e < 4; e++) {
        accA[e]    += a * r0[e]; accA[e+4]  += a * r1[e];
        accA[e+8]  += a * n0[e]; accA[e+12] += a * n1[e];
        accB[e]    += b * r0[e]; accB[e+4]  += b * r1[e];
        accB[e+8]  += b * n0[e]; accB[e+12] += b * n1[e];
      }
    }
  }
  #pragma unroll
  for (int k = 0; k < 16; k++) {
    float v = accA[k];
    for (int off = 32; off; off >>= 1) v += __shfl_xor(v, off);
    accA[k] = v;
    float u = accB[k];
    for (int off = 32; off; off >>= 1) u += __shfl_xor(u, off);
    accB[k] = u;
  }
  if (lane == 0) {
    #pragma unroll
    for (int tt = 0; tt < 2; tt++) {
      int t = t0 + tt;
      float noisy[8];
      #pragma unroll
      for (int e = 0; e < 8; e++) {
        float lg = (tt ? accB[e] : accA[e]) + br[e];
        float nl = (tt ? accB[e+8] : accA[e+8]) + bn[e];
        float sp = (nl > 0.f) ? nl + log1pf(expf(-nl)) : log1pf(expf(nl));
        noisy[e] = lg + noise[(size_t)t * 8 + e] * sp;
      }
      int e0 = 0; float v0 = noisy[0];
      #pragma unroll
      for (int e = 1; e < 8; e++) if (noisy[e] > v0) { v0 = noisy[e]; e0 = e; }
      int e1 = -1; float v1 = -1e30f;
      #pragma unroll
      for (int e = 0; e < 8; e++) if (e != e0 && noisy[e] > v1) { v1 = noisy[e]; e1 = e; }
      float g0 = 1.f / (1.f + expf(v1 - v0));
      topk_e[2*t] = e0; topk_e[2*t+1] = e1;
      topk_g[2*t] = g0; topk_g[2*t+1] = 1.f - g0;
    }
  }
}

// ---------------- deterministic scan: counts, 128-aligned offsets, rowmap ----------------
__global__ __launch_bounds__(1024) void scan_k(
    const int* __restrict__ topk_e, int* __restrict__ rowmap, int* __restrict__ aoffs)
{
  __shared__ int cnt[1024][8];
  __shared__ int tot[8];
  __shared__ int base[8];
  int tid = threadIdx.x;
  int ebuf[16];
  #pragma unroll
  for (int j = 0; j < 16; j++) ebuf[j] = topk_e[tid * 16 + j];
  int c0=0,c1=0,c2=0,c3=0,c4=0,c5=0,c6=0,c7=0;
  #pragma unroll
  for (int j = 0; j < 16; j++) {
    int e = ebuf[j];
    c0 += (e==0); c1 += (e==1); c2 += (e==2); c3 += (e==3);
    c4 += (e==4); c5 += (e==5); c6 += (e==6); c7 += (e==7);
  }
  cnt[tid][0]=c0; cnt[tid][1]=c1; cnt[tid][2]=c2; cnt[tid][3]=c3;
  cnt[tid][4]=c4; cnt[tid][5]=c5; cnt[tid][6]=c6; cnt[tid][7]=c7;
  __syncthreads();

  int w = tid >> 6, lane = tid & 63;
  if (w < 8) {
    int e = w;
    int s[16]; int run = 0;
    #pragma unroll
    for (int j = 0; j < 16; j++) { s[j] = run; run += cnt[lane*16+j][e]; }
    int inc = run;
    for (int off = 1; off < 64; off <<= 1) {
      int v = __shfl_up(inc, off);
      if (lane >= off) inc += v;
    }
    int lane_excl = inc - run;
    #pragma unroll
    for (int j = 0; j < 16; j++) cnt[lane*16+j][e] = lane_excl + s[j];
    if (lane == 63) tot[e] = inc;
  }
  __syncthreads();
  if (tid == 0) {
    int a = 0;
    for (int e = 0; e < 8; e++) { base[e] = a; aoffs[e] = a; a += (tot[e] + 127) & ~127; }
    aoffs[8] = a;
  }
  __syncthreads();
  int o0 = base[0]+cnt[tid][0], o1 = base[1]+cnt[tid][1], o2 = base[2]+cnt[tid][2],
      o3 = base[3]+cnt[tid][3], o4 = base[4]+cnt[tid][4], o5 = base[5]+cnt[tid][5],
      o6 = base[6]+cnt[tid][6], o7 = base[7]+cnt[tid][7];
  #pragma unroll
  for (int j = 0; j < 16; j++) {
    int e = ebuf[j];
    int row = o0;
    row = (e==1) ? o1 : row; row = (e==2) ? o2 : row; row = (e==3) ? o3 : row;
    row = (e==4) ? o4 : row; row = (e==5) ? o5 : row; row = (e==6) ? o6 : row;
    row = (e==7) ? o7 : row;
    o0 += (e==0); o1 += (e==1); o2 += (e==2); o3 += (e==3);
    o4 += (e==4); o5 += (e==5); o6 += (e==6); o7 += (e==7);
    rowmap[tid * 16 + j] = row;
  }
}

// ---------------- gather: one wave per token, write BOTH expert rows ----------------
__global__ __launch_bounds__(256) void gather_k(
    const float* __restrict__ x, const int* __restrict__ rowmap,
    u16* __restrict__ Xe)
{
  int w = threadIdx.x >> 6, lane = threadIdx.x & 63;
  int t = blockIdx.x * 4 + w;
  int r0 = rowmap[2*t], r1 = rowmap[2*t+1];
  const float4v* xs = (const float4v*)(x + (size_t)t * DIN);
  us4* d0 = (us4*)(Xe + (size_t)r0 * DIN);
  us4* d1 = (us4*)(Xe + (size_t)r1 * DIN);
  #pragma unroll
  for (int i = 0; i < DIN / 4 / 64; i++) {
    int q = i * 64 + lane;
    float4v v = xs[q];
    us4 o;
    #pragma unroll
    for (int j = 0; j < 4; j++) o[j] = f2bf(v[j]);
    d0[q] = o;
    d1[q] = o;
  }
}

// ---------------- 128x128 BK=64 4-wave MFMA GEMM v3: 2 barriers/tile, 2 blocks/CU ----------------
__global__ __launch_bounds__(256, 2) void gemm128_k(
    const u16* __restrict__ A, const u16* __restrict__ Bt,
    const float* __restrict__ bias, u16* __restrict__ Out,
    const int* __restrict__ aoffs, int K, int N, int relu)
{
  extern __shared__ u16 sm[];   // [2][ A:8192 u16 | B:8192 u16 ]

  int nwgx = gridDim.x;
  int id = blockIdx.y * nwgx + blockIdx.x;
  int per = (nwgx * gridDim.y) >> 3;
  int sid = (id & 7) * per + (id >> 3);
  int bx = sid % nwgx, by = sid / nwgx;

  int row0 = by * 128;
  if (row0 >= aoffs[NEXP]) return;
  int e = 0;
  #pragma unroll
  for (int i = 0; i < NEXP; i++) if (row0 >= aoffs[i + 1]) e = i + 1;
  int ncol0 = bx * 128;
  const u16* Ab = A + (size_t)row0 * K;
  const u16* Bb = Bt + ((size_t)e * N + ncol0) * K;

  int tid = threadIdx.x, w = tid >> 6, lane = tid & 63;
  int wr = w >> 1, wc = w & 1;
  int l15 = lane & 15, l4 = lane >> 4;
  int xorv = (l15 & 7) << 3;

  int srow[4], skc[4];
  #pragma unroll
  for (int q = 0; q < 4; q++) {
    int cd = q * 256 + tid;
    int cs = cd ^ ((cd >> 3) & 7);
    srow[q] = cs >> 3;
    skc[q]  = (cs & 7) * 8;
  }
  int ldsw = w * 1024;

  f32x4 acc[4][4];
  #pragma unroll
  for (int m = 0; m < 4; m++)
    #pragma unroll
    for (int n = 0; n < 4; n++) acc[m][n] = (f32x4){0.f, 0.f, 0.f, 0.f};

  short8 a[4][2], b0[2][2], b1[2][2];

#define STAGE_A(T, BUF) do {                                                  \
    char* d_ = (char*)sm + (BUF) * 32768;                                     \
    int ko_ = (T) * 64;                                                       \
    _Pragma("unroll")                                                         \
    for (int q = 0; q < 4; q++)                                               \
      gload16(Ab + (size_t)srow[q] * K + ko_ + skc[q], d_ + q*4096 + ldsw);   \
  } while (0)
#define STAGE_B(T, BUF) do {                                                  \
    char* d_ = (char*)sm + (BUF) * 32768 + 16384;                             \
    int ko_ = (T) * 64;                                                       \
    _Pragma("unroll")                                                         \
    for (int q = 0; q < 4; q++)                                               \
      gload16(Bb + (size_t)srow[q] * K + ko_ + skc[q], d_ + q*4096 + ldsw);   \
  } while (0)
#define RD_A() do {                                                           \
    _Pragma("unroll")                                                         \
    for (int m = 0; m < 4; m++)                                               \
      _Pragma("unroll")                                                       \
      for (int ks = 0; ks < 2; ks++) {                                        \
        int r_ = wr*64 + m*16 + l15;                                          \
        a[m][ks] = *(const short8*)&smA[(r_*64 + ks*32 + l4*8) ^ xorv];       \
      }                                                                       \
  } while (0)
#define RD_B(DST, NH) do {                                                    \
    _Pragma("unroll")                                                         \
    for (int n = 0; n < 2; n++)                                               \
      _Pragma("unroll")                                                       \
      for (int ks = 0; ks < 2; ks++) {                                        \
        int r_ = wc*64 + (NH)*32 + n*16 + l15;                                \
        DST[n][ks] = *(const short8*)&smB[(r_*64 + ks*32 + l4*8) ^ xorv];     \
      }                                                                       \
  } while (0)
#define MFMA16(NH, BB) do {                                                   \
    _Pragma("unroll")                                                         \
    for (int m = 0; m < 4; m++)                                               \
      _Pragma("unroll")                                                       \
      for (int n = 0; n < 2; n++)                                             \
        _Pragma("unroll")                                                     \
        for (int ks = 0; ks < 2; ks++)                                        \
          acc[m][(NH)*2+n] = __builtin_amdgcn_mfma_f32_16x16x32_bf16(         \
              a[m][ks], BB[n][ks], acc[m][(NH)*2+n], 0, 0, 0);                \
  } while (0)
#define BAR __builtin_amdgcn_s_barrier()

  int NT = K >> 6;
  STAGE_A(0, 0);
  STAGE_B(0, 0);
  STAGE_A(1, 1);
  STAGE_B(1, 1);
  asm volatile("s_waitcnt vmcnt(8)" ::: "memory");
  BAR;

  for (int t = 0; t < NT; ++t) {
    int buf = t & 1;
    const u16* smA = sm + buf * 16384;
    const u16* smB = smA + 8192;
    RD_A();
    RD_B(b0, 0);
    RD_B(b1, 1);
    asm volatile("s_waitcnt lgkmcnt(0)" ::: "memory");
    BAR;
    if (t + 2 < NT) {
      STAGE_A(t + 2, buf);
      STAGE_B(t + 2, buf);
    }
    __builtin_amdgcn_s_setprio(1);
    MFMA16(0, b0);
    MFMA16(1, b1);
    __builtin_amdgcn_s_setprio(0);
    if (t + 2 < NT) {
      asm volatile("s_waitcnt vmcnt(8)" ::: "memory");
    } else if (t + 1 < NT) {
      asm volatile("s_waitcnt vmcnt(0)" ::: "memory");
    }
    BAR;
  }
#undef STAGE_A
#undef STAGE_B
#undef RD_A
#undef RD_B
#undef MFMA16
#undef BAR

  #pragma unroll
  for (int in = 0; in < 4; in++) {
    int c = ncol0 + wc * 64 + in * 16 + l15;
    float bv = bias[(size_t)e * N + c];
    #pragma unroll
    for (int im = 0; im < 4; im++) {
      int rb = row0 + wr * 64 + im * 16 + l4 * 4;
      #pragma unroll
      for (int j = 0; j < 4; j++) {
        float v = acc[im][in][j] + bv;
        if (relu) v = fmaxf(v, 0.f);
        Out[(size_t)(rb + j) * N + c] = f2bf(v);
      }
    }
  }
}

// ---------------- residual + LN + gamma/beta + gated combine ----------------
__global__ __launch_bounds__(256) void ln_k(
    const float* __restrict__ x, const u16* __restrict__ Y,
    const int* __restrict__ rowmap, const int* __restrict__ topk_e,
    const float* __restrict__ topk_g, const float* __restrict__ gamma,
    const float* __restrict__ beta, float* __restrict__ out)
{
  __shared__ float red[4][4];
  int t = blockIdx.x, tid = threadIdx.x;
  int r0 = rowmap[2*t], r1 = rowmap[2*t+1];
  int e0 = topk_e[2*t], e1 = topk_e[2*t+1];
  float g0 = topk_g[2*t], g1 = topk_g[2*t+1];
  const float* xt = x + (size_t)t * DIN;
  const u16* y0p = Y + (size_t)r0 * DIN;
  const u16* y1p = Y + (size_t)r1 * DIN;
  float v0[5], v1[5];
  float s0 = 0.f, q0 = 0.f, s1 = 0.f, q1 = 0.f;
  #pragma unroll
  for (int i = 0; i < 5; i++) {
    int d = i * 256 + tid;
    float xv = xt[d];
    float a = xv + bf2f(y0p[d]);
    float b = xv + bf2f(y1p[d]);
    v0[i] = a; v1[i] = b;
    s0 += a; q0 += a * a; s1 += b; q1 += b * b;
  }
  for (int off = 32; off; off >>= 1) {
    s0 += __shfl_xor(s0, off); q0 += __shfl_xor(q0, off);
    s1 += __shfl_xor(s1, off); q1 += __shfl_xor(q1, off);
  }
  int w = tid >> 6, lane = tid & 63;
  if (lane == 0) { red[w][0] = s0; red[w][1] = q0; red[w][2] = s1; red[w][3] = q1; }
  __syncthreads();
  s0 = red[0][0] + red[1][0] + red[2][0] + red[3][0];
  q0 = red[0][1] + red[1][1] + red[2][1] + red[3][1];
  s1 = red[0][2] + red[1][2] + red[2][2] + red[3][2];
  q1 = red[0][3] + red[1][3] + red[2][3] + red[3][3];
  const float inv = 1.f / DIN;
  float mu0 = s0 * inv, mu1 = s1 * inv;
  float rs0 = rsqrtf(fmaxf(q0 * inv - mu0 * mu0, 0.f) + 1e-6f);
  float rs1 = rsqrtf(fmaxf(q1 * inv - mu1 * mu1, 0.f) + 1e-6f);
  const float* ga0 = gamma + (size_t)e0 * DIN;
  const float* be0 = beta  + (size_t)e0 * DIN;
  const float* ga1 = gamma + (size_t)e1 * DIN;
  const float* be1 = beta  + (size_t)e1 * DIN;
  #pragma unroll
  for (int i = 0; i < 5; i++) {
    int d = i * 256 + tid;
    float n0 = (v0[i] - mu0) * rs0 * ga0[d] + be0[d];
    float n1 = (v1[i] - mu1) * rs1 * ga1[d] + be1[d];
    out[(size_t)t * DIN + d] = g0 * n0 + g1 * n1;
  }
}

extern "C" void kernel_launch(void* const* d_in, const int* in_sizes, int n_in,
                              void* d_out, int out_size, void* d_ws, size_t ws_size,
                              hipStream_t stream)
{
  const float* x     = (const float*)d_in[0];
  const float* noise = (const float*)d_in[1];
  const float* wr    = (const float*)d_in[2];
  const float* br    = (const float*)d_in[3];
  const float* wn    = (const float*)d_in[4];
  const float* bn    = (const float*)d_in[5];
  const float* w1    = (const float*)d_in[6];
  const float* b1    = (const float*)d_in[7];
  const float* w2    = (const float*)d_in[8];
  const float* b2    = (const float*)d_in[9];
  const float* gamma = (const float*)d_in[10];
  const float* beta  = (const float*)d_in[11];
  float* out = (float*)d_out;
  char* ws = (char*)d_ws;

  int*   aoffs   = (int*)(ws + 128);
  int*   rowmap  = (int*)(ws + 4096);
  int*   topk_e  = (int*)(ws + 4096 + 65536);
  float* topk_g  = (float*)(ws + 4096 + 2 * 65536);

  const size_t XE_OFF   = (size_t)1 << 20;
  const size_t XE_BYTES = (size_t)RCAP * DIN * 2;   // 44.6 MB
  const size_t H_BYTES  = (size_t)RCAP * DHID * 2;  // 71.3 MB
  const size_t WT_BYTES = (size_t)NEXP * DHID * DIN * 2; // 41.9 MB each
  u16* Xe  = (u16*)(ws + XE_OFF);
  u16* Hb  = (u16*)(ws + XE_OFF + XE_BYTES);
  u16* Yb  = Xe;  // alias: Xe is dead after gemm1
  u16* W1t = (u16*)(ws + XE_OFF + XE_BYTES + H_BYTES);
  u16* W2t = (u16*)(ws + XE_OFF + XE_BYTES + H_BYTES + WT_BYTES);

  pre_k<<<TRBLK1 + TRBLK2 + RTRBLKS, 256, 0, stream>>>(
      w1, W1t, w2, W2t, x, noise, wr, br, wn, bn, topk_e, topk_g);
  scan_k<<<1, 1024, 0, stream>>>(topk_e, rowmap, aoffs);
  gather_k<<<TOK/4, 256, 0, stream>>>(x, rowmap, Xe);
  gemm128_k<<<dim3(DHID/128, MT128), 256, 65536, stream>>>(Xe, W1t, b1, Hb, aoffs, DIN, DHID, 1);
  gemm128_k<<<dim3(DIN/128, MT128), 256, 65536, stream>>>(Hb, W2t, b2, Yb, aoffs, DHID, DIN, 0);
  ln_k<<<TOK, 256, 0, stream>>>(x, Yb, rowmap, topk_e, topk_g, gamma, beta, out);
}

// Round 10
// 341.507 us; speedup vs baseline: 1.0603x; 1.0603x over previous
//
#include <hip/hip_runtime.h>
#include <stdint.h>

typedef unsigned short u16;
typedef __attribute__((ext_vector_type(8))) short short8;
typedef __attribute__((ext_vector_type(4))) float f32x4;
typedef __attribute__((ext_vector_type(4))) float float4v;
typedef __attribute__((ext_vector_type(4))) unsigned short us4;
typedef __attribute__((ext_vector_type(8))) unsigned short us8;

#define TOK   8192      // B*S
#define DIN   1280
#define DHID  2048
#define NEXP  8
#define RCAP  17408     // 16384 pairs + 8*128 worst-case alignment pad
#define MT128 136       // RCAP/128

#define TRBLK1 5120     // 8 experts * (1280/64) * (2048/64)
#define TRBLK2 5120     // 8 experts * (2048/64) * (1280/64)

__device__ __forceinline__ float bf2f(u16 u) {
  union { unsigned int i; float f; } v; v.i = ((unsigned int)u) << 16; return v.f;
}
__device__ __forceinline__ u16 f2bf(float f) {
  union { float f; unsigned int i; } v; v.f = f;
  unsigned int x = v.i;
  return (u16)((x + 0x7fffu + ((x >> 16) & 1u)) >> 16);
}

__device__ __forceinline__ void gload16(const u16* g, void* lds) {
  __builtin_amdgcn_global_load_lds(
      (const __attribute__((address_space(1))) unsigned int*)g,
      (__attribute__((address_space(3))) unsigned int*)lds, 16, 0, 0);
}

// ---------------- wide-IO weight transpose: [E,RK,CN] f32 -> [E,CN,RK] bf16 ----------------
__global__ __launch_bounds__(256) void tr_k(
    const float* __restrict__ w1, u16* __restrict__ W1t,
    const float* __restrict__ w2, u16* __restrict__ W2t)
{
  __shared__ u16 ldsT[64 * 72];   // [col][row], pad 72
  int id = blockIdx.x;
  int tid = threadIdx.x;
  int w = tid >> 6, lane = tid & 63;

  const float* in; u16* outp; int RK, CN, rb, cb;
  if (id < TRBLK1) {
    int e = id / 640, r = id % 640;
    RK = DIN; CN = DHID;                 // w1: [1280, 2048]
    rb = (r >> 5) * 64; cb = (r & 31) * 64;
    in = w1 + (size_t)e * RK * CN; outp = W1t + (size_t)e * RK * CN;
  } else {
    int id2 = id - TRBLK1;
    int e = id2 / 640, r = id2 % 640;
    RK = DHID; CN = DIN;                 // w2: [2048, 1280]
    rb = (r / 20) * 64; cb = (r % 20) * 64;
    in = w2 + (size_t)e * RK * CN; outp = W2t + (size_t)e * RK * CN;
  }
  {
    const float* src = in + (size_t)(rb + lane) * CN + cb + w * 16;
    u16 val[16];
    #pragma unroll
    for (int k = 0; k < 4; k++) {
      float4v v = *(const float4v*)(src + k * 4);
      #pragma unroll
      for (int j = 0; j < 4; j++) val[k * 4 + j] = f2bf(v[j]);
    }
    #pragma unroll
    for (int j = 0; j < 16; j++)
      ldsT[(w * 16 + j) * 72 + lane] = val[j];   // whole wave -> one column: 2 lanes/bank
  }
  __syncthreads();
  {
    int oc = tid >> 2, rch = (tid & 3) * 16;
    const u16* s = &ldsT[oc * 72 + rch];
    u16* d = outp + (size_t)(cb + oc) * RK + rb + rch;
    *(us8*)(d)     = *(const us8*)(s);
    *(us8*)(d + 8) = *(const us8*)(s + 8);
  }
}

// ---------------- router v3: paired-lane coalesced weight loads, no atomics ----------------
// lane l -> d = d0 + (l>>1), expert-half h = l&1. Weight loads are 1KB contiguous
// per wave-instruction (lane byte addr = d0*32 + l*16).
__global__ __launch_bounds__(256) void router_k(
    const float* __restrict__ x, const float* __restrict__ noise,
    const float* __restrict__ wr, const float* __restrict__ br,
    const float* __restrict__ wn, const float* __restrict__ bn,
    int* __restrict__ topk_e, float* __restrict__ topk_g)
{
  int w = threadIdx.x >> 6, lane = threadIdx.x & 63;
  int t0 = blockIdx.x * 8 + w * 2;
  int h = lane & 1, dl = lane >> 1;
  const float* xA = x + (size_t)t0 * DIN;
  const float* xB = xA + DIN;

  float ra[4], na[4], rb2[4], nb2[4];
  #pragma unroll
  for (int j = 0; j < 4; j++) { ra[j] = 0.f; na[j] = 0.f; rb2[j] = 0.f; nb2[j] = 0.f; }

  #pragma unroll 4
  for (int d0 = 0; d0 < DIN; d0 += 32) {
    int d = d0 + dl;
    float4v wrv = *(const float4v*)(wr + (size_t)d * 8 + h * 4);
    float4v wnv = *(const float4v*)(wn + (size_t)d * 8 + h * 4);
    float xa = xA[d], xb = xB[d];
    #pragma unroll
    for (int j = 0; j < 4; j++) {
      ra[j]  += xa * wrv[j]; na[j]  += xa * wnv[j];
      rb2[j] += xb * wrv[j]; nb2[j] += xb * wnv[j];
    }
  }
  // reduce over the 32 lanes sharing h (xor masks keep bit0)
  #pragma unroll
  for (int off = 2; off < 64; off <<= 1) {
    #pragma unroll
    for (int j = 0; j < 4; j++) {
      ra[j]  += __shfl_xor(ra[j],  off);
      na[j]  += __shfl_xor(na[j],  off);
      rb2[j] += __shfl_xor(rb2[j], off);
      nb2[j] += __shfl_xor(nb2[j], off);
    }
  }
  // pull the other half (lane0 <-> lane1)
  float raO[4], naO[4], rbO[4], nbO[4];
  #pragma unroll
  for (int j = 0; j < 4; j++) {
    raO[j] = __shfl_xor(ra[j], 1);
    naO[j] = __shfl_xor(na[j], 1);
    rbO[j] = __shfl_xor(rb2[j], 1);
    nbO[j] = __shfl_xor(nb2[j], 1);
  }
  if (lane == 0) {   // lane0: own=experts0-3, other=experts4-7; has both tokens
    #pragma unroll
    for (int tt = 0; tt < 2; tt++) {
      int t = t0 + tt;
      float noisy[8];
      #pragma unroll
      for (int j = 0; j < 4; j++) {
        float lg0 = (tt ? rb2[j] : ra[j]) + br[j];
        float nl0 = (tt ? nb2[j] : na[j]) + bn[j];
        float lg1 = (tt ? rbO[j] : raO[j]) + br[4 + j];
        float nl1 = (tt ? nbO[j] : naO[j]) + bn[4 + j];
        float sp0 = (nl0 > 0.f) ? nl0 + log1pf(expf(-nl0)) : log1pf(expf(nl0));
        float sp1 = (nl1 > 0.f) ? nl1 + log1pf(expf(-nl1)) : log1pf(expf(nl1));
        noisy[j]     = lg0 + noise[(size_t)t * 8 + j] * sp0;
        noisy[4 + j] = lg1 + noise[(size_t)t * 8 + 4 + j] * sp1;
      }
      int e0 = 0; float v0 = noisy[0];
      #pragma unroll
      for (int e = 1; e < 8; e++) if (noisy[e] > v0) { v0 = noisy[e]; e0 = e; }
      int e1 = -1; float v1 = -1e30f;
      #pragma unroll
      for (int e = 0; e < 8; e++) if (e != e0 && noisy[e] > v1) { v1 = noisy[e]; e1 = e; }
      float g0 = 1.f / (1.f + expf(v1 - v0));
      topk_e[2*t] = e0; topk_e[2*t+1] = e1;
      topk_g[2*t] = g0; topk_g[2*t+1] = 1.f - g0;
    }
  }
}

// ---------------- deterministic scan: counts, 128-aligned offsets, rowmap ----------------
__global__ __launch_bounds__(1024) void scan_k(
    const int* __restrict__ topk_e, int* __restrict__ rowmap, int* __restrict__ aoffs)
{
  __shared__ int cnt[1024][8];
  __shared__ int tot[8];
  __shared__ int base[8];
  int tid = threadIdx.x;
  int ebuf[16];
  #pragma unroll
  for (int j = 0; j < 16; j++) ebuf[j] = topk_e[tid * 16 + j];
  int c0=0,c1=0,c2=0,c3=0,c4=0,c5=0,c6=0,c7=0;
  #pragma unroll
  for (int j = 0; j < 16; j++) {
    int e = ebuf[j];
    c0 += (e==0); c1 += (e==1); c2 += (e==2); c3 += (e==3);
    c4 += (e==4); c5 += (e==5); c6 += (e==6); c7 += (e==7);
  }
  cnt[tid][0]=c0; cnt[tid][1]=c1; cnt[tid][2]=c2; cnt[tid][3]=c3;
  cnt[tid][4]=c4; cnt[tid][5]=c5; cnt[tid][6]=c6; cnt[tid][7]=c7;
  __syncthreads();

  int w = tid >> 6, lane = tid & 63;
  if (w < 8) {
    int e = w;
    int s[16]; int run = 0;
    #pragma unroll
    for (int j = 0; j < 16; j++) { s[j] = run; run += cnt[lane*16+j][e]; }
    int inc = run;
    for (int off = 1; off < 64; off <<= 1) {
      int v = __shfl_up(inc, off);
      if (lane >= off) inc += v;
    }
    int lane_excl = inc - run;
    #pragma unroll
    for (int j = 0; j < 16; j++) cnt[lane*16+j][e] = lane_excl + s[j];
    if (lane == 63) tot[e] = inc;
  }
  __syncthreads();
  if (tid == 0) {
    int a = 0;
    for (int e = 0; e < 8; e++) { base[e] = a; aoffs[e] = a; a += (tot[e] + 127) & ~127; }
    aoffs[8] = a;
  }
  __syncthreads();
  int o0 = base[0]+cnt[tid][0], o1 = base[1]+cnt[tid][1], o2 = base[2]+cnt[tid][2],
      o3 = base[3]+cnt[tid][3], o4 = base[4]+cnt[tid][4], o5 = base[5]+cnt[tid][5],
      o6 = base[6]+cnt[tid][6], o7 = base[7]+cnt[tid][7];
  #pragma unroll
  for (int j = 0; j < 16; j++) {
    int e = ebuf[j];
    int row = o0;
    row = (e==1) ? o1 : row; row = (e==2) ? o2 : row; row = (e==3) ? o3 : row;
    row = (e==4) ? o4 : row; row = (e==5) ? o5 : row; row = (e==6) ? o6 : row;
    row = (e==7) ? o7 : row;
    o0 += (e==0); o1 += (e==1); o2 += (e==2); o3 += (e==3);
    o4 += (e==4); o5 += (e==5); o6 += (e==6); o7 += (e==7);
    rowmap[tid * 16 + j] = row;
  }
}

// ---------------- gather: one wave per token, write BOTH expert rows ----------------
__global__ __launch_bounds__(256) void gather_k(
    const float* __restrict__ x, const int* __restrict__ rowmap,
    u16* __restrict__ Xe)
{
  int w = threadIdx.x >> 6, lane = threadIdx.x & 63;
  int t = blockIdx.x * 4 + w;
  int r0 = rowmap[2*t], r1 = rowmap[2*t+1];
  const float4v* xs = (const float4v*)(x + (size_t)t * DIN);
  us4* d0 = (us4*)(Xe + (size_t)r0 * DIN);
  us4* d1 = (us4*)(Xe + (size_t)r1 * DIN);
  #pragma unroll
  for (int i = 0; i < DIN / 4 / 64; i++) {
    int q = i * 64 + lane;
    float4v v = xs[q];
    us4 o;
    #pragma unroll
    for (int j = 0; j < 4; j++) o[j] = f2bf(v[j]);
    d0[q] = o;
    d1[q] = o;
  }
}

// ---------------- 128x128 BK=64 4-wave MFMA GEMM v3: 2 barriers/tile, 2 blocks/CU ----------------
__global__ __launch_bounds__(256, 2) void gemm128_k(
    const u16* __restrict__ A, const u16* __restrict__ Bt,
    const float* __restrict__ bias, u16* __restrict__ Out,
    const int* __restrict__ aoffs, int K, int N, int relu)
{
  extern __shared__ u16 sm[];   // [2][ A:8192 u16 | B:8192 u16 ]

  int nwgx = gridDim.x;
  int id = blockIdx.y * nwgx + blockIdx.x;
  int per = (nwgx * gridDim.y) >> 3;
  int sid = (id & 7) * per + (id >> 3);
  int bx = sid % nwgx, by = sid / nwgx;

  int row0 = by * 128;
  if (row0 >= aoffs[NEXP]) return;
  int e = 0;
  #pragma unroll
  for (int i = 0; i < NEXP; i++) if (row0 >= aoffs[i + 1]) e = i + 1;
  int ncol0 = bx * 128;
  const u16* Ab = A + (size_t)row0 * K;
  const u16* Bb = Bt + ((size_t)e * N + ncol0) * K;

  int tid = threadIdx.x, w = tid >> 6, lane = tid & 63;
  int wr = w >> 1, wc = w & 1;
  int l15 = lane & 15, l4 = lane >> 4;
  int xorv = (l15 & 7) << 3;

  int srow[4], skc[4];
  #pragma unroll
  for (int q = 0; q < 4; q++) {
    int cd = q * 256 + tid;
    int cs = cd ^ ((cd >> 3) & 7);
    srow[q] = cs >> 3;
    skc[q]  = (cs & 7) * 8;
  }
  int ldsw = w * 1024;

  f32x4 acc[4][4];
  #pragma unroll
  for (int m = 0; m < 4; m++)
    #pragma unroll
    for (int n = 0; n < 4; n++) acc[m][n] = (f32x4){0.f, 0.f, 0.f, 0.f};

  short8 a[4][2], b0[2][2], b1[2][2];

#define STAGE_A(T, BUF) do {                                                  \
    char* d_ = (char*)sm + (BUF) * 32768;                                     \
    int ko_ = (T) * 64;                                                       \
    _Pragma("unroll")                                                         \
    for (int q = 0; q < 4; q++)                                               \
      gload16(Ab + (size_t)srow[q] * K + ko_ + skc[q], d_ + q*4096 + ldsw);   \
  } while (0)
#define STAGE_B(T, BUF) do {                                                  \
    char* d_ = (char*)sm + (BUF) * 32768 + 16384;                             \
    int ko_ = (T) * 64;                                                       \
    _Pragma("unroll")                                                         \
    for (int q = 0; q < 4; q++)                                               \
      gload16(Bb + (size_t)srow[q] * K + ko_ + skc[q], d_ + q*4096 + ldsw);   \
  } while (0)
#define RD_A() do {                                                           \
    _Pragma("unroll")                                                         \
    for (int m = 0; m < 4; m++)                                               \
      _Pragma("unroll")                                                       \
      for (int ks = 0; ks < 2; ks++) {                                        \
        int r_ = wr*64 + m*16 + l15;                                          \
        a[m][ks] = *(const short8*)&smA[(r_*64 + ks*32 + l4*8) ^ xorv];       \
      }                                                                       \
  } while (0)
#define RD_B(DST, NH) do {                                                    \
    _Pragma("unroll")                                                         \
    for (int n = 0; n < 2; n++)                                               \
      _Pragma("unroll")                                                       \
      for (int ks = 0; ks < 2; ks++) {                                        \
        int r_ = wc*64 + (NH)*32 + n*16 + l15;                                \
        DST[n][ks] = *(const short8*)&smB[(r_*64 + ks*32 + l4*8) ^ xorv];     \
      }                                                                       \
  } while (0)
#define MFMA16(NH, BB) do {                                                   \
    _Pragma("unroll")                                                         \
    for (int m = 0; m < 4; m++)                                               \
      _Pragma("unroll")                                                       \
      for (int n = 0; n < 2; n++)                                             \
        _Pragma("unroll")                                                     \
        for (int ks = 0; ks < 2; ks++)                                        \
          acc[m][(NH)*2+n] = __builtin_amdgcn_mfma_f32_16x16x32_bf16(         \
              a[m][ks], BB[n][ks], acc[m][(NH)*2+n], 0, 0, 0);                \
  } while (0)
#define BAR __builtin_amdgcn_s_barrier()

  int NT = K >> 6;
  STAGE_A(0, 0);
  STAGE_B(0, 0);
  STAGE_A(1, 1);
  STAGE_B(1, 1);
  asm volatile("s_waitcnt vmcnt(8)" ::: "memory");
  BAR;

  for (int t = 0; t < NT; ++t) {
    int buf = t & 1;
    const u16* smA = sm + buf * 16384;
    const u16* smB = smA + 8192;
    RD_A();
    RD_B(b0, 0);
    RD_B(b1, 1);
    asm volatile("s_waitcnt lgkmcnt(0)" ::: "memory");
    BAR;
    if (t + 2 < NT) {
      STAGE_A(t + 2, buf);
      STAGE_B(t + 2, buf);
    }
    __builtin_amdgcn_s_setprio(1);
    MFMA16(0, b0);
    MFMA16(1, b1);
    __builtin_amdgcn_s_setprio(0);
    if (t + 2 < NT) {
      asm volatile("s_waitcnt vmcnt(8)" ::: "memory");
    } else if (t + 1 < NT) {
      asm volatile("s_waitcnt vmcnt(0)" ::: "memory");
    }
    BAR;
  }
#undef STAGE_A
#undef STAGE_B
#undef RD_A
#undef RD_B
#undef MFMA16
#undef BAR

  #pragma unroll
  for (int in = 0; in < 4; in++) {
    int c = ncol0 + wc * 64 + in * 16 + l15;
    float bv = bias[(size_t)e * N + c];
    #pragma unroll
    for (int im = 0; im < 4; im++) {
      int rb = row0 + wr * 64 + im * 16 + l4 * 4;
      #pragma unroll
      for (int j = 0; j < 4; j++) {
        float v = acc[im][in][j] + bv;
        if (relu) v = fmaxf(v, 0.f);
        Out[(size_t)(rb + j) * N + c] = f2bf(v);
      }
    }
  }
}

// ---------------- residual + LN + gamma/beta + gated combine ----------------
__global__ __launch_bounds__(256) void ln_k(
    const float* __restrict__ x, const u16* __restrict__ Y,
    const int* __restrict__ rowmap, const int* __restrict__ topk_e,
    const float* __restrict__ topk_g, const float* __restrict__ gamma,
    const float* __restrict__ beta, float* __restrict__ out)
{
  __shared__ float red[4][4];
  int t = blockIdx.x, tid = threadIdx.x;
  int r0 = rowmap[2*t], r1 = rowmap[2*t+1];
  int e0 = topk_e[2*t], e1 = topk_e[2*t+1];
  float g0 = topk_g[2*t], g1 = topk_g[2*t+1];
  const float* xt = x + (size_t)t * DIN;
  const u16* y0p = Y + (size_t)r0 * DIN;
  const u16* y1p = Y + (size_t)r1 * DIN;
  float v0[5], v1[5];
  float s0 = 0.f, q0 = 0.f, s1 = 0.f, q1 = 0.f;
  #pragma unroll
  for (int i = 0; i < 5; i++) {
    int d = i * 256 + tid;
    float xv = xt[d];
    float a = xv + bf2f(y0p[d]);
    float b = xv + bf2f(y1p[d]);
    v0[i] = a; v1[i] = b;
    s0 += a; q0 += a * a; s1 += b; q1 += b * b;
  }
  for (int off = 32; off; off >>= 1) {
    s0 += __shfl_xor(s0, off); q0 += __shfl_xor(q0, off);
    s1 += __shfl_xor(s1, off); q1 += __shfl_xor(q1, off);
  }
  int w = tid >> 6, lane = tid & 63;
  if (lane == 0) { red[w][0] = s0; red[w][1] = q0; red[w][2] = s1; red[w][3] = q1; }
  __syncthreads();
  s0 = red[0][0] + red[1][0] + red[2][0] + red[3][0];
  q0 = red[0][1] + red[1][1] + red[2][1] + red[3][1];
  s1 = red[0][2] + red[1][2] + red[2][2] + red[3][2];
  q1 = red[0][3] + red[1][3] + red[2][3] + red[3][3];
  const float inv = 1.f / DIN;
  float mu0 = s0 * inv, mu1 = s1 * inv;
  float rs0 = rsqrtf(fmaxf(q0 * inv - mu0 * mu0, 0.f) + 1e-6f);
  float rs1 = rsqrtf(fmaxf(q1 * inv - mu1 * mu1, 0.f) + 1e-6f);
  const float* ga0 = gamma + (size_t)e0 * DIN;
  const float* be0 = beta  + (size_t)e0 * DIN;
  const float* ga1 = gamma + (size_t)e1 * DIN;
  const float* be1 = beta  + (size_t)e1 * DIN;
  #pragma unroll
  for (int i = 0; i < 5; i++) {
    int d = i * 256 + tid;
    float n0 = (v0[i] - mu0) * rs0 * ga0[d] + be0[d];
    float n1 = (v1[i] - mu1) * rs1 * ga1[d] + be1[d];
    out[(size_t)t * DIN + d] = g0 * n0 + g1 * n1;
  }
}

extern "C" void kernel_launch(void* const* d_in, const int* in_sizes, int n_in,
                              void* d_out, int out_size, void* d_ws, size_t ws_size,
                              hipStream_t stream)
{
  const float* x     = (const float*)d_in[0];
  const float* noise = (const float*)d_in[1];
  const float* wr    = (const float*)d_in[2];
  const float* br    = (const float*)d_in[3];
  const float* wn    = (const float*)d_in[4];
  const float* bn    = (const float*)d_in[5];
  const float* w1    = (const float*)d_in[6];
  const float* b1    = (const float*)d_in[7];
  const float* w2    = (const float*)d_in[8];
  const float* b2    = (const float*)d_in[9];
  const float* gamma = (const float*)d_in[10];
  const float* beta  = (const float*)d_in[11];
  float* out = (float*)d_out;
  char* ws = (char*)d_ws;

  int*   aoffs   = (int*)(ws + 128);
  int*   rowmap  = (int*)(ws + 4096);
  int*   topk_e  = (int*)(ws + 4096 + 65536);
  float* topk_g  = (float*)(ws + 4096 + 2 * 65536);

  const size_t XE_OFF   = (size_t)1 << 20;
  const size_t XE_BYTES = (size_t)RCAP * DIN * 2;   // 44.6 MB
  const size_t H_BYTES  = (size_t)RCAP * DHID * 2;  // 71.3 MB
  const size_t WT_BYTES = (size_t)NEXP * DHID * DIN * 2; // 41.9 MB each
  u16* Xe  = (u16*)(ws + XE_OFF);
  u16* Hb  = (u16*)(ws + XE_OFF + XE_BYTES);
  u16* Yb  = Xe;  // alias: Xe is dead after gemm1
  u16* W1t = (u16*)(ws + XE_OFF + XE_BYTES + H_BYTES);
  u16* W2t = (u16*)(ws + XE_OFF + XE_BYTES + H_BYTES + WT_BYTES);

  router_k<<<TOK/8, 256, 0, stream>>>(x, noise, wr, br, wn, bn, topk_e, topk_g);
  scan_k<<<1, 1024, 0, stream>>>(topk_e, rowmap, aoffs);
  tr_k<<<TRBLK1 + TRBLK2, 256, 0, stream>>>(w1, W1t, w2, W2t);
  gather_k<<<TOK/4, 256, 0, stream>>>(x, rowmap, Xe);
  gemm128_k<<<dim3(DHID/128, MT128), 256, 65536, stream>>>(Xe, W1t, b1, Hb, aoffs, DIN, DHID, 1);
  gemm128_k<<<dim3(DIN/128, MT128), 256, 65536, stream>>>(Hb, W2t, b2, Yb, aoffs, DHID, DIN, 0);
  ln_k<<<TOK, 256, 0, stream>>>(x, Yb, rowmap, topk_e, topk_g, gamma, beta, out);
}